// Round 1
// baseline (702.394 us; speedup 1.0000x reference)
//
#include <hip/hip_runtime.h>

// PrototypeBank steady-state update, MI355X/gfx950.
//   emb:    [131072, 512] fp32   protos: [1024, 512] fp32
//   out:    [1024, 512] fp32 = where(count>0, normalize(0.9*p + 0.1*cluster_mean(e)), p)
// Pipeline:
//   k0: normalize protos -> bf16 (ws)
//   k1: fused normalize(emb)->bf16 LDS tile + MFMA sims + argmax -> assign, invnorm
//   k2: per-proto gather of assigned rows (fp32) -> mean -> EMA -> normalize -> out

#define D 512
#define NPROTO 1024
#define ROWS 64          // embedding rows per workgroup in k1
#define CHUNK 16384      // scan chunk in k2
#define QCAP 8192        // LDS queue capacity in k2

typedef __attribute__((ext_vector_type(8))) unsigned short ushort8;
typedef __attribute__((ext_vector_type(8))) __bf16 bfrag8;
typedef __attribute__((ext_vector_type(4))) float f32x4;

static __device__ inline unsigned short f2bf(float f) {
    unsigned int u = __float_as_uint(f);
    u = u + 0x7FFFu + ((u >> 16) & 1u);   // round-to-nearest-even
    return (unsigned short)(u >> 16);
}

// ---------------- k0: normalize prototypes to bf16 ----------------
__global__ __launch_bounds__(256) void norm_protos_kernel(
    const float* __restrict__ protos, unsigned short* __restrict__ pbf)
{
    const int wave = threadIdx.x >> 6, lane = threadIdx.x & 63;
    const int row = blockIdx.x * 4 + wave;            // grid 256 -> 1024 rows
    const float* src = protos + (size_t)row * D + lane * 8;
    float4 v0 = *(const float4*)src;
    float4 v1 = *(const float4*)(src + 4);
    float ss = v0.x*v0.x + v0.y*v0.y + v0.z*v0.z + v0.w*v0.w
             + v1.x*v1.x + v1.y*v1.y + v1.z*v1.z + v1.w*v1.w;
    #pragma unroll
    for (int off = 32; off > 0; off >>= 1) ss += __shfl_xor(ss, off, 64);
    const float inv = 1.0f / fmaxf(sqrtf(ss), 1e-6f);
    ushort8 w;
    w[0] = f2bf(v0.x*inv); w[1] = f2bf(v0.y*inv); w[2] = f2bf(v0.z*inv); w[3] = f2bf(v0.w*inv);
    w[4] = f2bf(v1.x*inv); w[5] = f2bf(v1.y*inv); w[6] = f2bf(v1.z*inv); w[7] = f2bf(v1.w*inv);
    *(ushort8*)(pbf + (size_t)row * D + lane * 8) = w;
}

// ---------------- k1: normalize + argmax over 1024 protos (bf16 MFMA) ----------------
// LDS tile: 64 rows x 512 bf16, 16B-chunk XOR swizzle (slot = chunk ^ (row&7))
// -> conflict-free ds_read_b128 A-fragments AND conflict-free staging writes.
__global__ __launch_bounds__(256, 2) void assign_kernel(
    const float* __restrict__ emb, const unsigned short* __restrict__ pbf,
    int* __restrict__ assign, float* __restrict__ invnorm)
{
    __shared__ __align__(16) unsigned short eT[ROWS * D];   // 64 KB
    const int tid = threadIdx.x;
    const int wave = tid >> 6, lane = tid & 63;
    const int rowbase = blockIdx.x * ROWS;
    const int cl = lane & 15, quad = lane >> 4;

    // --- stage: each wave normalizes 16 rows; lane holds 8 contiguous floats (chunk = lane)
    for (int rr = 0; rr < 16; ++rr) {
        const int rloc = wave * 16 + rr;
        const float* src = emb + (size_t)(rowbase + rloc) * D + lane * 8;
        float4 v0 = *(const float4*)src;
        float4 v1 = *(const float4*)(src + 4);
        float ss = v0.x*v0.x + v0.y*v0.y + v0.z*v0.z + v0.w*v0.w
                 + v1.x*v1.x + v1.y*v1.y + v1.z*v1.z + v1.w*v1.w;
        #pragma unroll
        for (int off = 32; off > 0; off >>= 1) ss += __shfl_xor(ss, off, 64);
        const float inv = 1.0f / fmaxf(sqrtf(ss), 1e-6f);
        if (lane == 0) invnorm[rowbase + rloc] = inv;
        ushort8 w;
        w[0] = f2bf(v0.x*inv); w[1] = f2bf(v0.y*inv); w[2] = f2bf(v0.z*inv); w[3] = f2bf(v0.w*inv);
        w[4] = f2bf(v1.x*inv); w[5] = f2bf(v1.y*inv); w[6] = f2bf(v1.z*inv); w[7] = f2bf(v1.w*inv);
        const int slot = lane ^ (rloc & 7);
        *(ushort8*)(&eT[rloc * D + slot * 8]) = w;
    }
    __syncthreads();

    // --- main: wave owns proto quarter [wave*256, +256) ; 4 Msub x 4 Nsub MFMA tiles
    float rmax[4][4];
    int   ridx[4][4];
    #pragma unroll
    for (int m = 0; m < 4; ++m)
        #pragma unroll
        for (int r = 0; r < 4; ++r) { rmax[m][r] = -3.4e38f; ridx[m][r] = 0; }

    const int colq = wave * 256;
    for (int ng = 0; ng < 4; ++ng) {
        const int colbase = colq + ng * 64;
        f32x4 acc[4][4];
        #pragma unroll
        for (int m = 0; m < 4; ++m)
            #pragma unroll
            for (int n = 0; n < 4; ++n) acc[m][n] = (f32x4){0.f, 0.f, 0.f, 0.f};

        #pragma unroll 2
        for (int ks = 0; ks < 16; ++ks) {
            bfrag8 a[4], b[4];
            #pragma unroll
            for (int m = 0; m < 4; ++m) {
                const int rloc = m * 16 + cl;
                const int slot = (ks * 4 + quad) ^ (rloc & 7);
                a[m] = *(const bfrag8*)(&eT[rloc * D + slot * 8]);
            }
            #pragma unroll
            for (int n = 0; n < 4; ++n) {
                const unsigned short* bp =
                    pbf + (size_t)(colbase + n * 16 + cl) * D + ks * 32 + quad * 8;
                b[n] = *(const bfrag8*)bp;
            }
            #pragma unroll
            for (int n = 0; n < 4; ++n)
                #pragma unroll
                for (int m = 0; m < 4; ++m)
                    acc[m][n] = __builtin_amdgcn_mfma_f32_16x16x32_bf16(a[m], b[n], acc[m][n], 0, 0, 0);
        }
        // fold this 64-proto group into running argmax (C layout: col=lane&15, row=quad*4+reg)
        #pragma unroll
        for (int n = 0; n < 4; ++n) {
            const int idx = colbase + n * 16 + cl;
            #pragma unroll
            for (int m = 0; m < 4; ++m)
                #pragma unroll
                for (int r = 0; r < 4; ++r) {
                    const float v = acc[m][n][r];
                    if (v > rmax[m][r] || (v == rmax[m][r] && idx < ridx[m][r])) {
                        rmax[m][r] = v; ridx[m][r] = idx;
                    }
                }
        }
    }

    // --- reduce across the 16 column-lanes of each quad
    #pragma unroll
    for (int m = 0; m < 4; ++m)
        #pragma unroll
        for (int r = 0; r < 4; ++r) {
            float v = rmax[m][r]; int idx = ridx[m][r];
            #pragma unroll
            for (int off = 1; off < 16; off <<= 1) {
                const float ov = __shfl_xor(v, off, 64);
                const int   oi = __shfl_xor(idx, off, 64);
                if (ov > v || (ov == v && oi < idx)) { v = ov; idx = oi; }
            }
            rmax[m][r] = v; ridx[m][r] = idx;
        }

    __syncthreads();                       // all waves done reading eT
    float* swmax = (float*)eT;             // [4][64]  bytes [0,1024)
    int*   swidx = (int*)&eT[512];         // [4][64]  bytes [1024,2048)
    if (cl == 0) {
        #pragma unroll
        for (int m = 0; m < 4; ++m)
            #pragma unroll
            for (int r = 0; r < 4; ++r) {
                const int lrow = m * 16 + quad * 4 + r;
                swmax[wave * 64 + lrow] = rmax[m][r];
                swidx[wave * 64 + lrow] = ridx[m][r];
            }
    }
    __syncthreads();
    if (tid < 64) {
        float v = swmax[tid]; int idx = swidx[tid];
        #pragma unroll
        for (int w = 1; w < 4; ++w) {
            const float ov = swmax[w * 64 + tid];
            const int   oi = swidx[w * 64 + tid];
            if (ov > v || (ov == v && oi < idx)) { v = ov; idx = oi; }
        }
        assign[rowbase + tid] = idx;
    }
}

// ---------------- k2: per-proto gather mean + EMA + normalize ----------------
__global__ __launch_bounds__(256) void update_kernel(
    const float* __restrict__ emb, const float* __restrict__ protos,
    const int* __restrict__ assign, const float* __restrict__ invnorm,
    float* __restrict__ out, int n_emb)
{
    __shared__ int qbuf[QCAP];
    __shared__ int qcnt;
    __shared__ float red[4];
    const int k = blockIdx.x, t = threadIdx.x;
    float acc0 = 0.f, acc1 = 0.f;
    int total = 0;

    for (int base = 0; base < n_emb; base += CHUNK) {
        if (t == 0) qcnt = 0;
        __syncthreads();
        #pragma unroll
        for (int j = 0; j < CHUNK / 1024; ++j) {
            const int i = base + (j * 256 + t) * 4;
            const int4 a = *(const int4*)(assign + i);
            if (a.x == k) { int p = atomicAdd(&qcnt, 1); if (p < QCAP) qbuf[p] = i; }
            if (a.y == k) { int p = atomicAdd(&qcnt, 1); if (p < QCAP) qbuf[p] = i + 1; }
            if (a.z == k) { int p = atomicAdd(&qcnt, 1); if (p < QCAP) qbuf[p] = i + 2; }
            if (a.w == k) { int p = atomicAdd(&qcnt, 1); if (p < QCAP) qbuf[p] = i + 3; }
        }
        __syncthreads();
        int cnt = qcnt; if (cnt > QCAP) cnt = QCAP;
        total += cnt;
        int m = 0;
        for (; m + 4 <= cnt; m += 4) {
            const int r0 = qbuf[m], r1 = qbuf[m+1], r2 = qbuf[m+2], r3 = qbuf[m+3];
            const float s0 = invnorm[r0], s1 = invnorm[r1], s2 = invnorm[r2], s3 = invnorm[r3];
            const float2 v0 = *(const float2*)(emb + (size_t)r0 * D + 2 * t);
            const float2 v1 = *(const float2*)(emb + (size_t)r1 * D + 2 * t);
            const float2 v2 = *(const float2*)(emb + (size_t)r2 * D + 2 * t);
            const float2 v3 = *(const float2*)(emb + (size_t)r3 * D + 2 * t);
            acc0 += v0.x * s0; acc1 += v0.y * s0;
            acc0 += v1.x * s1; acc1 += v1.y * s1;
            acc0 += v2.x * s2; acc1 += v2.y * s2;
            acc0 += v3.x * s3; acc1 += v3.y * s3;
        }
        for (; m < cnt; ++m) {
            const int r = qbuf[m];
            const float s = invnorm[r];
            const float2 v = *(const float2*)(emb + (size_t)r * D + 2 * t);
            acc0 += v.x * s; acc1 += v.y * s;
        }
        __syncthreads();
    }

    const float denom = fmaxf((float)total, 1.0f);
    const float m0 = acc0 / denom, m1 = acc1 / denom;
    const float p0 = protos[(size_t)k * D + 2 * t];
    const float p1 = protos[(size_t)k * D + 2 * t + 1];
    const float u0 = 0.9f * p0 + 0.1f * m0;
    const float u1 = 0.9f * p1 + 0.1f * m1;
    float ss = u0 * u0 + u1 * u1;
    #pragma unroll
    for (int off = 32; off > 0; off >>= 1) ss += __shfl_xor(ss, off, 64);
    if ((t & 63) == 0) red[t >> 6] = ss;
    __syncthreads();
    const float tot = red[0] + red[1] + red[2] + red[3];
    const float inv = 1.0f / fmaxf(sqrtf(tot), 1e-6f);
    out[(size_t)k * D + 2 * t]     = (total > 0) ? u0 * inv : p0;
    out[(size_t)k * D + 2 * t + 1] = (total > 0) ? u1 * inv : p1;
}

extern "C" void kernel_launch(void* const* d_in, const int* in_sizes, int n_in,
                              void* d_out, int out_size, void* d_ws, size_t ws_size,
                              hipStream_t stream)
{
    const float* emb    = (const float*)d_in[0];
    const float* protos = (const float*)d_in[1];
    float* out = (float*)d_out;
    const int n_emb = in_sizes[0] / D;        // 131072

    unsigned short* pbf = (unsigned short*)d_ws;                          // 1 MB
    int*   assign  = (int*)  ((char*)d_ws + (1 << 20));                   // 512 KB
    float* invnorm = (float*)((char*)d_ws + (1 << 20) + (512 << 10));     // 512 KB

    norm_protos_kernel<<<NPROTO / 4, 256, 0, stream>>>(protos, pbf);
    assign_kernel<<<n_emb / ROWS, 256, 0, stream>>>(emb, pbf, assign, invnorm);
    update_kernel<<<NPROTO, 256, 0, stream>>>(emb, protos, assign, invnorm, out, n_emb);
}

// Round 2
// 617.119 us; speedup vs baseline: 1.1382x; 1.1382x over previous
//
#include <hip/hip_runtime.h>

// PrototypeBank steady-state update, MI355X/gfx950.  Round 2.
//   emb:    [131072, 512] fp32   protos: [1024, 512] fp32
//   out[k]: count>0 ? normalize(0.9*p + 0.1*mean(norm_emb assigned to k)) : p
//
// Pipeline (5 dispatches):
//   k0 norm_protos:  normalize protos -> bf16 in MFMA-fragment-packed layout; zero counts
//   k1 assign:       normalize(emb)->LDS bf16 tile, MFMA sims vs 1024 protos, argmax
//                    (512 thr / 8 waves / 64KB LDS -> 16 waves/CU), += counts
//   k2 prefix:       exclusive prefix sum of counts -> offsets, cursor
//   k3 scatter:      bin[cursor[assign[i]]++] = i
//   k4 update:       per-proto gather of its bin rows -> mean -> EMA -> normalize -> out

#define D 512
#define NPROTO 1024
#define ROWS 64          // embedding rows per workgroup in k1

typedef __attribute__((ext_vector_type(8))) unsigned short ushort8;
typedef __attribute__((ext_vector_type(8))) __bf16 bfrag8;
typedef __attribute__((ext_vector_type(4))) float f32x4;

static __device__ inline unsigned short f2bf(float f) {
    unsigned int u = __float_as_uint(f);
    u = u + 0x7FFFu + ((u >> 16) & 1u);   // round-to-nearest-even
    return (unsigned short)(u >> 16);
}

// ---------------- k0: normalize prototypes -> packed bf16 fragments ----------------
// Packed layout: for proto-group g (16 protos) and k-step ks (32 cols), a 1KB chunk
// holding lane l = quad*16+cl -> row g*16+cl, cols ks*32+quad*8.  Consumer lane
// reads chunk_base + lane*16B: fully coalesced.
__global__ __launch_bounds__(256) void norm_protos_kernel(
    const float* __restrict__ protos, unsigned short* __restrict__ pbf,
    int* __restrict__ counts)
{
    const int wave = threadIdx.x >> 6, lane = threadIdx.x & 63;
    const int row = blockIdx.x * 4 + wave;            // grid 256 -> 1024 rows
    const float* src = protos + (size_t)row * D + lane * 8;
    float4 v0 = *(const float4*)src;
    float4 v1 = *(const float4*)(src + 4);
    float ss = v0.x*v0.x + v0.y*v0.y + v0.z*v0.z + v0.w*v0.w
             + v1.x*v1.x + v1.y*v1.y + v1.z*v1.z + v1.w*v1.w;
    #pragma unroll
    for (int off = 32; off > 0; off >>= 1) ss += __shfl_xor(ss, off, 64);
    const float inv = 1.0f / fmaxf(sqrtf(ss), 1e-6f);
    ushort8 w;
    w[0] = f2bf(v0.x*inv); w[1] = f2bf(v0.y*inv); w[2] = f2bf(v0.z*inv); w[3] = f2bf(v0.w*inv);
    w[4] = f2bf(v1.x*inv); w[5] = f2bf(v1.y*inv); w[6] = f2bf(v1.z*inv); w[7] = f2bf(v1.w*inv);
    const int g = row >> 4, cl = row & 15;
    const int ks = lane >> 2, q = lane & 3;           // lane holds cols [lane*8, +8)
    *(ushort8*)(pbf + (size_t)(g * 16 + ks) * 512 + (q * 16 + cl) * 8) = w;
    if (blockIdx.x == 0) ((int4*)counts)[threadIdx.x] = (int4){0, 0, 0, 0};
}

// ---------------- k1: normalize + argmax over 1024 protos (bf16 MFMA) ----------------
// LDS A-tile: 64 rows x 512 bf16, 16B-chunk XOR swizzle (slot = chunk ^ (row&7)).
// 8 waves/block; wave owns 128 protos (2 groups of 64, 4x4 MFMA subtiles each).
__global__ __launch_bounds__(512, 4) void assign_kernel(
    const float* __restrict__ emb, const unsigned short* __restrict__ pbf,
    int* __restrict__ assign, float* __restrict__ invnorm, int* __restrict__ counts)
{
    __shared__ __align__(16) unsigned short eT[ROWS * D];   // 64 KB
    const int tid = threadIdx.x;
    const int wave = tid >> 6, lane = tid & 63;
    const int rowbase = blockIdx.x * ROWS;
    const int cl = lane & 15, quad = lane >> 4;

    // --- stage: each wave normalizes 8 rows; lane holds 8 contiguous floats
    for (int rr = 0; rr < 8; ++rr) {
        const int rloc = wave * 8 + rr;
        const float* src = emb + (size_t)(rowbase + rloc) * D + lane * 8;
        float4 v0 = *(const float4*)src;
        float4 v1 = *(const float4*)(src + 4);
        float ss = v0.x*v0.x + v0.y*v0.y + v0.z*v0.z + v0.w*v0.w
                 + v1.x*v1.x + v1.y*v1.y + v1.z*v1.z + v1.w*v1.w;
        #pragma unroll
        for (int off = 32; off > 0; off >>= 1) ss += __shfl_xor(ss, off, 64);
        const float inv = 1.0f / fmaxf(sqrtf(ss), 1e-6f);
        if (lane == 0) invnorm[rowbase + rloc] = inv;
        ushort8 w;
        w[0] = f2bf(v0.x*inv); w[1] = f2bf(v0.y*inv); w[2] = f2bf(v0.z*inv); w[3] = f2bf(v0.w*inv);
        w[4] = f2bf(v1.x*inv); w[5] = f2bf(v1.y*inv); w[6] = f2bf(v1.z*inv); w[7] = f2bf(v1.w*inv);
        const int slot = lane ^ (rloc & 7);
        *(ushort8*)(&eT[rloc * D + slot * 8]) = w;
    }
    __syncthreads();

    // --- main: wave owns protos [wave*128, +128)
    float rmax[4][4];
    int   ridx[4][4];
    #pragma unroll
    for (int m = 0; m < 4; ++m)
        #pragma unroll
        for (int r = 0; r < 4; ++r) { rmax[m][r] = -3.4e38f; ridx[m][r] = 0; }

    const int colq = wave * 128;
    const unsigned short* bb = pbf + (size_t)colq * 512 + lane * 8;  // packed frags

    for (int ng = 0; ng < 2; ++ng) {
        const int colbase = colq + ng * 64;
        const unsigned short* bg = bb + (size_t)ng * 64 * 512;
        f32x4 acc[4][4];
        #pragma unroll
        for (int m = 0; m < 4; ++m)
            #pragma unroll
            for (int n = 0; n < 4; ++n) acc[m][n] = (f32x4){0.f, 0.f, 0.f, 0.f};

        #pragma unroll 2
        for (int ks = 0; ks < 16; ++ks) {
            bfrag8 a[4], b[4];
            #pragma unroll
            for (int m = 0; m < 4; ++m) {
                const int rloc = m * 16 + cl;
                const int slot = (ks * 4 + quad) ^ (rloc & 7);
                a[m] = *(const bfrag8*)(&eT[rloc * D + slot * 8]);
            }
            #pragma unroll
            for (int n = 0; n < 4; ++n)
                b[n] = *(const bfrag8*)(bg + n * 8192 + ks * 512);   // 1KB coalesced
            #pragma unroll
            for (int n = 0; n < 4; ++n)
                #pragma unroll
                for (int m = 0; m < 4; ++m)
                    acc[m][n] = __builtin_amdgcn_mfma_f32_16x16x32_bf16(a[m], b[n], acc[m][n], 0, 0, 0);
        }
        // fold (C layout: col=lane&15, row=quad*4+reg). Scan order is idx-ascending
        // per cell, so strict > keeps the first max (jnp.argmax semantics).
        #pragma unroll
        for (int n = 0; n < 4; ++n) {
            const int idx = colbase + n * 16 + cl;
            #pragma unroll
            for (int m = 0; m < 4; ++m)
                #pragma unroll
                for (int r = 0; r < 4; ++r) {
                    const float v = acc[m][n][r];
                    if (v > rmax[m][r]) { rmax[m][r] = v; ridx[m][r] = idx; }
                }
        }
    }

    // --- reduce across the 16 column-lanes of each quad (order arbitrary -> tie-break)
    #pragma unroll
    for (int m = 0; m < 4; ++m)
        #pragma unroll
        for (int r = 0; r < 4; ++r) {
            float v = rmax[m][r]; int idx = ridx[m][r];
            #pragma unroll
            for (int off = 1; off < 16; off <<= 1) {
                const float ov = __shfl_xor(v, off, 64);
                const int   oi = __shfl_xor(idx, off, 64);
                if (ov > v || (ov == v && oi < idx)) { v = ov; idx = oi; }
            }
            rmax[m][r] = v; ridx[m][r] = idx;
        }

    __syncthreads();                       // all waves done reading eT
    float* swmax = (float*)eT;             // [8][64]  bytes [0,2048)
    int*   swidx = (int*)&eT[1024];        // [8][64]  bytes [2048,4096)
    if (cl == 0) {
        #pragma unroll
        for (int m = 0; m < 4; ++m)
            #pragma unroll
            for (int r = 0; r < 4; ++r) {
                const int lrow = m * 16 + quad * 4 + r;
                swmax[wave * 64 + lrow] = rmax[m][r];
                swidx[wave * 64 + lrow] = ridx[m][r];
            }
    }
    __syncthreads();
    if (tid < 64) {
        float v = swmax[tid]; int idx = swidx[tid];
        #pragma unroll
        for (int w = 1; w < 8; ++w) {
            const float ov = swmax[w * 64 + tid];
            const int   oi = swidx[w * 64 + tid];
            if (ov > v || (ov == v && oi < idx)) { v = ov; idx = oi; }
        }
        assign[rowbase + tid] = idx;
        atomicAdd(&counts[idx], 1);
    }
}

// ---------------- k2: exclusive prefix sum of counts ----------------
__global__ __launch_bounds__(1024) void prefix_kernel(
    const int* __restrict__ counts, int* __restrict__ offsets, int* __restrict__ cursor)
{
    __shared__ int sc[NPROTO];
    const int t = threadIdx.x;
    const int c = counts[t];
    sc[t] = c;
    __syncthreads();
    #pragma unroll
    for (int off = 1; off < NPROTO; off <<= 1) {
        const int v = (t >= off) ? sc[t - off] : 0;
        __syncthreads();
        sc[t] += v;
        __syncthreads();
    }
    const int excl = sc[t] - c;
    offsets[t] = excl;
    cursor[t]  = excl;
}

// ---------------- k3: scatter row indices into per-proto bins ----------------
__global__ __launch_bounds__(256) void scatter_kernel(
    const int* __restrict__ assign, int* __restrict__ cursor, int* __restrict__ bin)
{
    const int i = blockIdx.x * 256 + threadIdx.x;
    const int k = assign[i];
    const int pos = atomicAdd(&cursor[k], 1);
    bin[pos] = i;
}

// ---------------- k4: per-proto gather mean + EMA + normalize ----------------
__global__ __launch_bounds__(256) void update_kernel(
    const float* __restrict__ emb, const float* __restrict__ protos,
    const int* __restrict__ bin, const int* __restrict__ counts,
    const int* __restrict__ offsets, const float* __restrict__ invnorm,
    float* __restrict__ out)
{
    __shared__ float red[4];
    const int k = blockIdx.x, t = threadIdx.x;
    const int cnt = counts[k], off = offsets[k];
    float acc0 = 0.f, acc1 = 0.f;

    int j = 0;
    for (; j + 4 <= cnt; j += 4) {
        const int r0 = bin[off + j],     r1 = bin[off + j + 1];
        const int r2 = bin[off + j + 2], r3 = bin[off + j + 3];
        const float s0 = invnorm[r0], s1 = invnorm[r1];
        const float s2 = invnorm[r2], s3 = invnorm[r3];
        const float2 v0 = *(const float2*)(emb + (size_t)r0 * D + 2 * t);
        const float2 v1 = *(const float2*)(emb + (size_t)r1 * D + 2 * t);
        const float2 v2 = *(const float2*)(emb + (size_t)r2 * D + 2 * t);
        const float2 v3 = *(const float2*)(emb + (size_t)r3 * D + 2 * t);
        acc0 += v0.x * s0; acc1 += v0.y * s0;
        acc0 += v1.x * s1; acc1 += v1.y * s1;
        acc0 += v2.x * s2; acc1 += v2.y * s2;
        acc0 += v3.x * s3; acc1 += v3.y * s3;
    }
    for (; j < cnt; ++j) {
        const int r = bin[off + j];
        const float s = invnorm[r];
        const float2 v = *(const float2*)(emb + (size_t)r * D + 2 * t);
        acc0 += v.x * s; acc1 += v.y * s;
    }

    const float denom = fmaxf((float)cnt, 1.0f);
    const float m0 = acc0 / denom, m1 = acc1 / denom;
    const float p0 = protos[(size_t)k * D + 2 * t];
    const float p1 = protos[(size_t)k * D + 2 * t + 1];
    const float u0 = 0.9f * p0 + 0.1f * m0;
    const float u1 = 0.9f * p1 + 0.1f * m1;
    float ss = u0 * u0 + u1 * u1;
    #pragma unroll
    for (int off2 = 32; off2 > 0; off2 >>= 1) ss += __shfl_xor(ss, off2, 64);
    if ((t & 63) == 0) red[t >> 6] = ss;
    __syncthreads();
    const float tot = red[0] + red[1] + red[2] + red[3];
    const float inv = 1.0f / fmaxf(sqrtf(tot), 1e-6f);
    out[(size_t)k * D + 2 * t]     = (cnt > 0) ? u0 * inv : p0;
    out[(size_t)k * D + 2 * t + 1] = (cnt > 0) ? u1 * inv : p1;
}

extern "C" void kernel_launch(void* const* d_in, const int* in_sizes, int n_in,
                              void* d_out, int out_size, void* d_ws, size_t ws_size,
                              hipStream_t stream)
{
    const float* emb    = (const float*)d_in[0];
    const float* protos = (const float*)d_in[1];
    float* out = (float*)d_out;
    const int n_emb = in_sizes[0] / D;        // 131072

    char* ws = (char*)d_ws;
    unsigned short* pbf = (unsigned short*)ws;                 // 1 MB packed bf16 protos
    int*   assign  = (int*)  (ws + (1 << 20));                 // 512 KB
    float* invnorm = (float*)(ws + (1 << 20) + (512 << 10));   // 512 KB
    int*   counts  = (int*)  (ws + (2 << 20));                 // 4 KB
    int*   offsets = (int*)  (ws + (2 << 20) + (4 << 10));     // 4 KB
    int*   cursor  = (int*)  (ws + (2 << 20) + (8 << 10));     // 4 KB
    int*   bin     = (int*)  (ws + (2 << 20) + (12 << 10));    // 512 KB

    norm_protos_kernel<<<NPROTO / 4, 256, 0, stream>>>(protos, pbf, counts);
    assign_kernel<<<n_emb / ROWS, 512, 0, stream>>>(emb, pbf, assign, invnorm, counts);
    prefix_kernel<<<1, 1024, 0, stream>>>(counts, offsets, cursor);
    scatter_kernel<<<n_emb / 256, 256, 0, stream>>>(assign, cursor, bin);
    update_kernel<<<NPROTO, 256, 0, stream>>>(emb, protos, bin, counts, offsets, invnorm, out);
}